// Round 2
// baseline (63.951 us; speedup 1.0000x reference)
//
#include <hip/hip_runtime.h>
#include <cstdint>
#include <cstddef>

typedef int v4i __attribute__((ext_vector_type(4)));

#define QMIN_F (-128.0f)
#define QMAX_F (127.0f)
#define SMALL_THR 6.1e-05f

// ---------------------------------------------------------------------------
// Kernel 0: pack int32-on-device qweight (harness passes integer inputs as
// int32) into contiguous int8. n4 = N*K/4; each lane packs 4 values.
// ---------------------------------------------------------------------------
__global__ __launch_bounds__(256) void pack_w_kernel(
    const int* __restrict__ w32, int* __restrict__ w8, int n4) {
  int i = blockIdx.x * blockDim.x + threadIdx.x;
  if (i >= n4) return;
  v4i v = *(const v4i*)(w32 + i * 4);
  w8[i] = (v.x & 255) | ((v.y & 255) << 8) | ((v.z & 255) << 16) | (v.w << 24);
}

// ---------------------------------------------------------------------------
// Kernel 1: per-row dynamic quantization. One wave (64 lanes) per row, K=1024.
// Each lane owns 16 elements as 4 x float4 at element offset j*256 + lane*4.
// ---------------------------------------------------------------------------
__global__ __launch_bounds__(256) void quant_rows_kernel(
    const float* __restrict__ x, signed char* __restrict__ q,
    float* __restrict__ scales, int* __restrict__ zps, int* __restrict__ sums,
    int K) {
  const int wave = threadIdx.x >> 6;
  const int lane = threadIdx.x & 63;
  const int row  = blockIdx.x * 4 + wave;
  const float* xr = x + (size_t)row * K;

  float4 v[4];
  float vmin = 0.0f, vmax = 0.0f, vsum = 0.0f;  // ref clamps min<=0, max>=0
#pragma unroll
  for (int j = 0; j < 4; ++j) {
    v[j] = *(const float4*)(xr + j * 256 + lane * 4);
    vmin = fminf(vmin, fminf(fminf(v[j].x, v[j].y), fminf(v[j].z, v[j].w)));
    vmax = fmaxf(vmax, fmaxf(fmaxf(v[j].x, v[j].y), fmaxf(v[j].z, v[j].w)));
    vsum += (v[j].x + v[j].y) + (v[j].z + v[j].w);
  }
#pragma unroll
  for (int off = 32; off >= 1; off >>= 1) {
    vmin = fminf(vmin, __shfl_xor(vmin, off));
    vmax = fmaxf(vmax, __shfl_xor(vmax, off));
    vsum += __shfl_xor(vsum, off);
  }

  // --- replicate reference scale/zero-point semantics exactly ---
  float scale = (vmax - vmin) / (QMAX_F - QMIN_F);
  // faithful: scale == (0.0 + isinf(1/scale))  [dead in practice, kept literal]
  float isinf_f = isinf(1.0f / scale) ? 1.0f : 0.0f;
  if (scale == isinf_f) scale = 0.1f;
  float rmin = vmin, rmax = vmax;
  if (scale < SMALL_THR) {
    float amp = SMALL_THR / scale;
    scale = SMALL_THR;
    rmax *= amp;
    rmin *= amp;
  }
  float rdmin = rmin / scale, rdmax = rmax / scale;
  float err_min = 128.0f + fabsf(rdmin);
  float err_max = 127.0f + fabsf(rdmax);
  float zp0 = (err_min < err_max) ? (QMIN_F - rdmin) : (QMAX_F - rdmax);
  int zp = (int)rintf(zp0);               // RNE matches jnp.round
  if (zp0 < QMIN_F) zp = -128;
  if (zp0 > QMAX_F) zp = 127;
  float inv = 1.0f / scale;

  if (lane == 0) {
    scales[row] = scale;
    zps[row]    = zp;
    sums[row]   = (int)rintf(vsum * inv);
  }

  const float zpf = (float)zp;
  int* qi = (int*)(q + (size_t)row * K);
#pragma unroll
  for (int j = 0; j < 4; ++j) {
    float t0 = fminf(fmaxf(rintf(v[j].x * inv) + zpf, QMIN_F), QMAX_F);
    float t1 = fminf(fmaxf(rintf(v[j].y * inv) + zpf, QMIN_F), QMAX_F);
    float t2 = fminf(fmaxf(rintf(v[j].z * inv) + zpf, QMIN_F), QMAX_F);
    float t3 = fminf(fmaxf(rintf(v[j].w * inv) + zpf, QMIN_F), QMAX_F);
    int pack = ((int)t0 & 255) | (((int)t1 & 255) << 8) |
               (((int)t2 & 255) << 16) | ((int)t3 << 24);
    qi[j * 64 + lane] = pack;  // byte offset j*256 + lane*4: coalesced 256B
  }
}

// ---------------------------------------------------------------------------
// Kernel 2: int8 GEMM (A=q [M,K], B=w [N,K], both K-major) + fused dequant.
// BM=BN=128, BK=64, 4 waves, each wave owns a 64x64 output sub-tile,
// mfma_i32_16x16x64_i8. LDS staged via global_load_lds width=16 with a
// 16B-slot XOR swizzle (slot ^= row&3) applied on source AND read side.
// ---------------------------------------------------------------------------
__device__ __forceinline__ void gload_lds16(const void* g, void* l) {
  __builtin_amdgcn_global_load_lds(
      (const __attribute__((address_space(1))) void*)g,
      (__attribute__((address_space(3))) void*)l, 16, 0, 0);
}

__global__ __launch_bounds__(256) void gemm_dequant_kernel(
    const signed char* __restrict__ q, const signed char* __restrict__ w,
    const float* __restrict__ scales, const int* __restrict__ zps,
    const int* __restrict__ sums, const float* __restrict__ bias,
    const float* __restrict__ w_scales, const int* __restrict__ w_zeros,
    const int* __restrict__ w_sums, float* __restrict__ out,
    int N, int K) {
  __shared__ signed char sA[128 * 64];
  __shared__ signed char sB[128 * 64];
  const int tid  = threadIdx.x;
  const int lane = tid & 63;
  const int wave = tid >> 6;
  const int ntN   = N >> 7;
  const int tileM = (int)blockIdx.x / ntN;
  const int tileN = (int)blockIdx.x % ntN;
  const int rowA0 = tileM << 7;
  const int rowB0 = tileN << 7;
  const int wr = wave >> 1, wc = wave & 1;
  const int fr = lane & 15;   // row/col within 16
  const int kb = lane >> 4;   // 16-byte K-slot 0..3

  v4i acc[4][4];
#pragma unroll
  for (int i = 0; i < 4; ++i)
#pragma unroll
    for (int j = 0; j < 4; ++j) {
      v4i z = {0, 0, 0, 0};
      acc[i][j] = z;
    }

  const int nkt = K >> 6;
  for (int kt = 0; kt < nkt; ++kt) {
    const int k0 = kt << 6;
    // stage: 512 chunks of 16B per matrix; LDS dest linear (base+lane*16),
    // source pre-swizzled so LDS[row][slot] holds global (row, slot^(row&3)).
#pragma unroll
    for (int s = 0; s < 2; ++s) {
      int c  = (s << 8) + tid;
      int r  = c >> 2;
      int sl = (c & 3) ^ (r & 3);
      int go = k0 + (sl << 4);
      gload_lds16(q + (size_t)(rowA0 + r) * K + go, sA + (c << 4));
      gload_lds16(w + (size_t)(rowB0 + r) * K + go, sB + (c << 4));
    }
    __syncthreads();

    v4i a[4], b[4];
#pragma unroll
    for (int f = 0; f < 4; ++f) {
      int ra = (wr << 6) + (f << 4) + fr;
      a[f] = *(const v4i*)(sA + (ra << 6) + ((kb ^ (ra & 3)) << 4));
      int rb = (wc << 6) + (f << 4) + fr;
      b[f] = *(const v4i*)(sB + (rb << 6) + ((kb ^ (rb & 3)) << 4));
    }
#pragma unroll
    for (int i = 0; i < 4; ++i)
#pragma unroll
      for (int j = 0; j < 4; ++j)
        acc[i][j] =
            __builtin_amdgcn_mfma_i32_16x16x64_i8(a[i], b[j], acc[i][j], 0, 0, 0);
    __syncthreads();
  }

  // Epilogue: C/D layout col = lane&15, row = (lane>>4)*4 + reg.
  const int baseM = rowA0 + (wr << 6);
  const int baseN = rowB0 + (wc << 6);
#pragma unroll
  for (int i = 0; i < 4; ++i) {
    const int m0 = baseM + (i << 4) + ((lane >> 4) << 2);
    float sc[4];
    int zp4[4], sm4[4];
#pragma unroll
    for (int j = 0; j < 4; ++j) {
      sc[j]  = scales[m0 + j];
      zp4[j] = zps[m0 + j];
      sm4[j] = sums[m0 + j];
    }
#pragma unroll
    for (int jj = 0; jj < 4; ++jj) {
      const int n = baseN + (jj << 4) + (lane & 15);
      const float bs  = bias[n];
      const float wsc = w_scales[n];
      const int   wz  = w_zeros[n];
      const int   ws  = w_sums[n];
#pragma unroll
      for (int j = 0; j < 4; ++j) {
        int d    = acc[i][jj][j];
        int temp = zp4[j] * ws + sm4[j] * wz;
        out[(size_t)(m0 + j) * N + n] = bs + (float)(d - temp) * (sc[j] * wsc);
      }
    }
  }
}

extern "C" void kernel_launch(void* const* d_in, const int* in_sizes, int n_in,
                              void* d_out, int out_size, void* d_ws, size_t ws_size,
                              hipStream_t stream) {
  const float* inp      = (const float*)d_in[0];
  const int*   qw32     = (const int*)d_in[1];   // int8 in ref -> int32 on device
  const float* bias     = (const float*)d_in[2];
  const float* w_scales = (const float*)d_in[3];
  const int*   w_zeros  = (const int*)d_in[4];
  const int*   w_sums   = (const int*)d_in[5];

  const int N = in_sizes[2];      // 1024 (bias length)
  const int K = in_sizes[1] / N;  // 1024
  const int M = in_sizes[0] / K;  // 16384

  float*       scales = (float*)d_ws;
  int*         zps    = (int*)((char*)d_ws + (size_t)M * 4);
  int*         sums   = (int*)((char*)d_ws + (size_t)M * 8);
  signed char* q      = (signed char*)((char*)d_ws + (size_t)M * 12);
  signed char* w8     = (signed char*)((char*)d_ws + (size_t)M * 12 + (size_t)M * K);

  const int n4 = (N * K) / 4;
  pack_w_kernel<<<(n4 + 255) / 256, 256, 0, stream>>>(qw32, (int*)w8, n4);
  quant_rows_kernel<<<M / 4, 256, 0, stream>>>(inp, q, scales, zps, sums, K);
  gemm_dequant_kernel<<<(M / 128) * (N / 128), 256, 0, stream>>>(
      q, w8, scales, zps, sums, bias, w_scales, w_zeros, w_sums,
      (float*)d_out, N, K);
}

// Round 3
// 53.306 us; speedup vs baseline: 1.1997x; 1.1997x over previous
//
#include <hip/hip_runtime.h>
#include <cstdint>
#include <cstddef>

typedef int v4i __attribute__((ext_vector_type(4)));

#define QMIN_F (-128.0f)
#define QMAX_F (127.0f)
#define SMALL_THR 6.1e-05f

#define WAITVM(n) asm volatile("s_waitcnt vmcnt(" #n ")" ::: "memory")

// ---------------------------------------------------------------------------
// Kernel 0: pack int32-on-device qweight into contiguous int8.
// ---------------------------------------------------------------------------
__global__ __launch_bounds__(256) void pack_w_kernel(
    const int* __restrict__ w32, int* __restrict__ w8, int n4) {
  int i = blockIdx.x * blockDim.x + threadIdx.x;
  if (i >= n4) return;
  v4i v = *(const v4i*)(w32 + i * 4);
  w8[i] = (v.x & 255) | ((v.y & 255) << 8) | ((v.z & 255) << 16) | (v.w << 24);
}

// ---------------------------------------------------------------------------
// Kernel 1: per-row dynamic quantization (unchanged from passing R2).
// ---------------------------------------------------------------------------
__global__ __launch_bounds__(256) void quant_rows_kernel(
    const float* __restrict__ x, signed char* __restrict__ q,
    float* __restrict__ scales, int* __restrict__ zps, int* __restrict__ sums,
    int K) {
  const int wave = threadIdx.x >> 6;
  const int lane = threadIdx.x & 63;
  const int row  = blockIdx.x * 4 + wave;
  const float* xr = x + (size_t)row * K;

  float4 v[4];
  float vmin = 0.0f, vmax = 0.0f, vsum = 0.0f;
#pragma unroll
  for (int j = 0; j < 4; ++j) {
    v[j] = *(const float4*)(xr + j * 256 + lane * 4);
    vmin = fminf(vmin, fminf(fminf(v[j].x, v[j].y), fminf(v[j].z, v[j].w)));
    vmax = fmaxf(vmax, fmaxf(fmaxf(v[j].x, v[j].y), fmaxf(v[j].z, v[j].w)));
    vsum += (v[j].x + v[j].y) + (v[j].z + v[j].w);
  }
#pragma unroll
  for (int off = 32; off >= 1; off >>= 1) {
    vmin = fminf(vmin, __shfl_xor(vmin, off));
    vmax = fmaxf(vmax, __shfl_xor(vmax, off));
    vsum += __shfl_xor(vsum, off);
  }

  float scale = (vmax - vmin) / (QMAX_F - QMIN_F);
  float isinf_f = isinf(1.0f / scale) ? 1.0f : 0.0f;
  if (scale == isinf_f) scale = 0.1f;
  float rmin = vmin, rmax = vmax;
  if (scale < SMALL_THR) {
    float amp = SMALL_THR / scale;
    scale = SMALL_THR;
    rmax *= amp;
    rmin *= amp;
  }
  float rdmin = rmin / scale, rdmax = rmax / scale;
  float err_min = 128.0f + fabsf(rdmin);
  float err_max = 127.0f + fabsf(rdmax);
  float zp0 = (err_min < err_max) ? (QMIN_F - rdmin) : (QMAX_F - rdmax);
  int zp = (int)rintf(zp0);
  if (zp0 < QMIN_F) zp = -128;
  if (zp0 > QMAX_F) zp = 127;
  float inv = 1.0f / scale;

  if (lane == 0) {
    scales[row] = scale;
    zps[row]    = zp;
    sums[row]   = (int)rintf(vsum * inv);
  }

  const float zpf = (float)zp;
  int* qi = (int*)(q + (size_t)row * K);
#pragma unroll
  for (int j = 0; j < 4; ++j) {
    float t0 = fminf(fmaxf(rintf(v[j].x * inv) + zpf, QMIN_F), QMAX_F);
    float t1 = fminf(fmaxf(rintf(v[j].y * inv) + zpf, QMIN_F), QMAX_F);
    float t2 = fminf(fmaxf(rintf(v[j].z * inv) + zpf, QMIN_F), QMAX_F);
    float t3 = fminf(fmaxf(rintf(v[j].w * inv) + zpf, QMIN_F), QMAX_F);
    int pack = ((int)t0 & 255) | (((int)t1 & 255) << 8) |
               (((int)t2 & 255) << 16) | ((int)t3 << 24);
    qi[j * 64 + lane] = pack;
  }
}

// ---------------------------------------------------------------------------
// Kernel 2: int8 GEMM + fused dequant, 256x256 tile, 8 waves (2Mx4N),
// BK=64, 3-buffer LDS pipeline with counted vmcnt (stage t+2 during t).
// Swizzle: 16B slot sl' = sl ^ ((row>>1)&3) on BOTH gload source and ds_read.
// ---------------------------------------------------------------------------
__device__ __forceinline__ void gload_lds16(const void* g, void* l) {
  __builtin_amdgcn_global_load_lds(
      (const __attribute__((address_space(1))) void*)g,
      (__attribute__((address_space(3))) void*)l, 16, 0, 0);
}

__device__ __forceinline__ void stage_tile(
    const signed char* __restrict__ q, const signed char* __restrict__ w,
    char* bufA, char* bufB, int rowA0, int rowB0, int k0, int K, int tid) {
#pragma unroll
  for (int i = 0; i < 2; ++i) {
    int c  = (i << 9) + tid;                 // 0..1023: A chunks (256 rows x 4)
    int r  = c >> 2;
    int sl = (c & 3) ^ ((r >> 1) & 3);
    gload_lds16(q + (size_t)(rowA0 + r) * K + k0 + (sl << 4), bufA + (c << 4));
  }
#pragma unroll
  for (int i = 0; i < 2; ++i) {
    int c  = (i << 9) + tid;                 // 0..1023: B chunks
    int r  = c >> 2;
    int sl = (c & 3) ^ ((r >> 1) & 3);
    gload_lds16(w + (size_t)(rowB0 + r) * K + k0 + (sl << 4), bufB + (c << 4));
  }
}

__global__ __launch_bounds__(512, 2) void gemm_dequant_kernel(
    const signed char* __restrict__ q, const signed char* __restrict__ w,
    const float* __restrict__ scales, const int* __restrict__ zps,
    const int* __restrict__ sums, const float* __restrict__ bias,
    const float* __restrict__ w_scales, const int* __restrict__ w_zeros,
    const int* __restrict__ w_sums, float* __restrict__ out,
    int N, int K) {
  __shared__ char sh[3][32768];              // per buffer: A 16K | B 16K
  const int tid  = threadIdx.x;
  const int lane = tid & 63;
  const int wave = tid >> 6;
  const int wr = wave >> 2;                  // 0..1  (M half)
  const int wc = wave & 3;                   // 0..3  (N quarter)
  const int fr = lane & 15;
  const int kb = lane >> 4;                  // 16B K-slot 0..3
  const int ntN = N >> 8;                    // 4
  const int rowA0 = ((int)blockIdx.x / ntN) << 8;
  const int rowB0 = ((int)blockIdx.x % ntN) << 8;
  const int wrbase = wr << 7;                // wave row base in tile
  const int wcbase = wc << 6;                // wave col base in tile

  v4i acc[8][4];
#pragma unroll
  for (int i = 0; i < 8; ++i)
#pragma unroll
    for (int j = 0; j < 4; ++j) {
      v4i z = {0, 0, 0, 0};
      acc[i][j] = z;
    }

  const int NT = K >> 6;                     // 16 K-tiles
  stage_tile(q, w, sh[0], sh[0] + 16384, rowA0, rowB0, 0, K, tid);
  stage_tile(q, w, sh[1], sh[1] + 16384, rowA0, rowB0, 64, K, tid);

  for (int t = 0; t < NT; ++t) {
    if (t + 2 < NT) {
      int b = (t + 2) % 3;
      stage_tile(q, w, sh[b], sh[b] + 16384, rowA0, rowB0, (t + 2) << 6, K, tid);
    }
    // counted wait: oldest 4 loads (this tile's) done; future tiles stay in flight
    if (t < NT - 2)      { WAITVM(8); }
    else if (t == NT - 2){ WAITVM(4); }
    else                 { WAITVM(0); }
    __builtin_amdgcn_s_barrier();

    const char* bA = sh[t % 3];
    const char* bB = bA + 16384;

    v4i bfrag[4], afrag[4];
#pragma unroll
    for (int n = 0; n < 4; ++n) {
      int rb = wcbase + (n << 4) + fr;
      bfrag[n] = *(const v4i*)(bB + (rb << 6) + ((kb ^ ((rb >> 1) & 3)) << 4));
    }
#pragma unroll
    for (int m = 0; m < 4; ++m) {
      int ra = wrbase + (m << 4) + fr;
      afrag[m] = *(const v4i*)(bA + (ra << 6) + ((kb ^ ((ra >> 1) & 3)) << 4));
    }
    __builtin_amdgcn_s_barrier();
    __builtin_amdgcn_s_setprio(1);
#pragma unroll
    for (int m = 0; m < 4; ++m)
#pragma unroll
      for (int n = 0; n < 4; ++n)
        acc[m][n] = __builtin_amdgcn_mfma_i32_16x16x64_i8(afrag[m], bfrag[n],
                                                          acc[m][n], 0, 0, 0);
    __builtin_amdgcn_s_setprio(0);
#pragma unroll
    for (int m = 0; m < 4; ++m) {
      int ra = wrbase + ((m + 4) << 4) + fr;
      afrag[m] = *(const v4i*)(bA + (ra << 6) + ((kb ^ ((ra >> 1) & 3)) << 4));
    }
    __builtin_amdgcn_s_barrier();
    __builtin_amdgcn_s_setprio(1);
#pragma unroll
    for (int m = 0; m < 4; ++m)
#pragma unroll
      for (int n = 0; n < 4; ++n)
        acc[m + 4][n] = __builtin_amdgcn_mfma_i32_16x16x64_i8(
            afrag[m], bfrag[n], acc[m + 4][n], 0, 0, 0);
    __builtin_amdgcn_s_setprio(0);
    asm volatile("" ::: "memory");
    __builtin_amdgcn_s_barrier();            // end-of-tile: buf[t%3] free
  }

  // Epilogue: C/D layout col = lane&15, row = (lane>>4)*4 + reg.
  const int baseM = rowA0 + wrbase;
  const int baseN = rowB0 + wcbase;
  const int qr = (lane >> 4) << 2;
  const int qc = lane & 15;
  float cb[4], cwsc[4];
  int cwz[4], cws[4];
#pragma unroll
  for (int n = 0; n < 4; ++n) {
    int col = baseN + (n << 4) + qc;
    cb[n]   = bias[col];
    cwsc[n] = w_scales[col];
    cwz[n]  = w_zeros[col];
    cws[n]  = w_sums[col];
  }
#pragma unroll
  for (int i = 0; i < 8; ++i) {
    const int m0 = baseM + (i << 4) + qr;
    float sc[4];
    int zp4[4], sm4[4];
#pragma unroll
    for (int j = 0; j < 4; ++j) {
      sc[j]  = scales[m0 + j];
      zp4[j] = zps[m0 + j];
      sm4[j] = sums[m0 + j];
    }
#pragma unroll
    for (int n = 0; n < 4; ++n) {
      const int col = baseN + (n << 4) + qc;
#pragma unroll
      for (int j = 0; j < 4; ++j) {
        int d    = acc[i][n][j];
        int temp = zp4[j] * cws[n] + sm4[j] * cwz[n];
        out[(size_t)(m0 + j) * N + col] = cb[n] + (float)(d - temp) * (sc[j] * cwsc[n]);
      }
    }
  }
}

extern "C" void kernel_launch(void* const* d_in, const int* in_sizes, int n_in,
                              void* d_out, int out_size, void* d_ws, size_t ws_size,
                              hipStream_t stream) {
  const float* inp      = (const float*)d_in[0];
  const int*   qw32     = (const int*)d_in[1];   // int8 in ref -> int32 on device
  const float* bias     = (const float*)d_in[2];
  const float* w_scales = (const float*)d_in[3];
  const int*   w_zeros  = (const int*)d_in[4];
  const int*   w_sums   = (const int*)d_in[5];

  const int N = in_sizes[2];      // 1024
  const int K = in_sizes[1] / N;  // 1024
  const int M = in_sizes[0] / K;  // 16384

  float*       scales = (float*)d_ws;
  int*         zps    = (int*)((char*)d_ws + (size_t)M * 4);
  int*         sums   = (int*)((char*)d_ws + (size_t)M * 8);
  signed char* q      = (signed char*)((char*)d_ws + (size_t)M * 12);
  signed char* w8     = (signed char*)((char*)d_ws + (size_t)M * 12 + (size_t)M * K);

  const int n4 = (N * K) / 4;
  pack_w_kernel<<<(n4 + 255) / 256, 256, 0, stream>>>(qw32, (int*)w8, n4);
  quant_rows_kernel<<<M / 4, 256, 0, stream>>>(inp, q, scales, zps, sums, K);
  gemm_dequant_kernel<<<(M / 256) * (N / 256), 512, 0, stream>>>(
      q, w8, scales, zps, sums, bias, w_scales, w_zeros, w_sums,
      (float*)d_out, N, K);
}

// Round 4
// 51.163 us; speedup vs baseline: 1.2500x; 1.0419x over previous
//
#include <hip/hip_runtime.h>
#include <cstdint>
#include <cstddef>

typedef int v4i __attribute__((ext_vector_type(4)));

#define QMIN_F (-128.0f)
#define QMAX_F (127.0f)
#define SMALL_THR 6.1e-05f

#define WAITVM(n) asm volatile("s_waitcnt vmcnt(" #n ")" ::: "memory")

// ---------------------------------------------------------------------------
// Kernel 0: pack int32-on-device qweight into contiguous int8.
// ---------------------------------------------------------------------------
__global__ __launch_bounds__(256) void pack_w_kernel(
    const int* __restrict__ w32, int* __restrict__ w8, int n4) {
  int i = blockIdx.x * blockDim.x + threadIdx.x;
  if (i >= n4) return;
  v4i v = *(const v4i*)(w32 + i * 4);
  w8[i] = (v.x & 255) | ((v.y & 255) << 8) | ((v.z & 255) << 16) | (v.w << 24);
}

// ---------------------------------------------------------------------------
// Kernel 1: per-row dynamic quantization (unchanged, passing).
// ---------------------------------------------------------------------------
__global__ __launch_bounds__(256) void quant_rows_kernel(
    const float* __restrict__ x, signed char* __restrict__ q,
    float* __restrict__ scales, int* __restrict__ zps, int* __restrict__ sums,
    int K) {
  const int wave = threadIdx.x >> 6;
  const int lane = threadIdx.x & 63;
  const int row  = blockIdx.x * 4 + wave;
  const float* xr = x + (size_t)row * K;

  float4 v[4];
  float vmin = 0.0f, vmax = 0.0f, vsum = 0.0f;
#pragma unroll
  for (int j = 0; j < 4; ++j) {
    v[j] = *(const float4*)(xr + j * 256 + lane * 4);
    vmin = fminf(vmin, fminf(fminf(v[j].x, v[j].y), fminf(v[j].z, v[j].w)));
    vmax = fmaxf(vmax, fmaxf(fmaxf(v[j].x, v[j].y), fmaxf(v[j].z, v[j].w)));
    vsum += (v[j].x + v[j].y) + (v[j].z + v[j].w);
  }
#pragma unroll
  for (int off = 32; off >= 1; off >>= 1) {
    vmin = fminf(vmin, __shfl_xor(vmin, off));
    vmax = fmaxf(vmax, __shfl_xor(vmax, off));
    vsum += __shfl_xor(vsum, off);
  }

  float scale = (vmax - vmin) / (QMAX_F - QMIN_F);
  float isinf_f = isinf(1.0f / scale) ? 1.0f : 0.0f;
  if (scale == isinf_f) scale = 0.1f;
  float rmin = vmin, rmax = vmax;
  if (scale < SMALL_THR) {
    float amp = SMALL_THR / scale;
    scale = SMALL_THR;
    rmax *= amp;
    rmin *= amp;
  }
  float rdmin = rmin / scale, rdmax = rmax / scale;
  float err_min = 128.0f + fabsf(rdmin);
  float err_max = 127.0f + fabsf(rdmax);
  float zp0 = (err_min < err_max) ? (QMIN_F - rdmin) : (QMAX_F - rdmax);
  int zp = (int)rintf(zp0);
  if (zp0 < QMIN_F) zp = -128;
  if (zp0 > QMAX_F) zp = 127;
  float inv = 1.0f / scale;

  if (lane == 0) {
    scales[row] = scale;
    zps[row]    = zp;
    sums[row]   = (int)rintf(vsum * inv);
  }

  const float zpf = (float)zp;
  int* qi = (int*)(q + (size_t)row * K);
#pragma unroll
  for (int j = 0; j < 4; ++j) {
    float t0 = fminf(fmaxf(rintf(v[j].x * inv) + zpf, QMIN_F), QMAX_F);
    float t1 = fminf(fmaxf(rintf(v[j].y * inv) + zpf, QMIN_F), QMAX_F);
    float t2 = fminf(fmaxf(rintf(v[j].z * inv) + zpf, QMIN_F), QMAX_F);
    float t3 = fminf(fmaxf(rintf(v[j].w * inv) + zpf, QMIN_F), QMAX_F);
    int pack = ((int)t0 & 255) | (((int)t1 & 255) << 8) |
               (((int)t2 & 255) << 16) | ((int)t3 << 24);
    qi[j * 64 + lane] = pack;
  }
}

// ---------------------------------------------------------------------------
// Kernel 2: int8 GEMM + fused dequant, 256x256 tile, 8 waves (2Mx4N),
// BK=64, 3-buffer LDS pipeline with counted vmcnt (stage t+2 during t).
// XCD-chunked blockIdx swizzle: XCD x owns tileM [8x,8x+8) x all 4 tileN ->
// A-panel footprint 2MB + w 1MB fits the 4MB per-XCD L2 (A fetched once).
// Swizzle: 16B slot sl' = sl ^ ((row>>1)&3) on BOTH gload source and ds_read.
// ---------------------------------------------------------------------------
__device__ __forceinline__ void gload_lds16(const void* g, void* l) {
  __builtin_amdgcn_global_load_lds(
      (const __attribute__((address_space(1))) void*)g,
      (__attribute__((address_space(3))) void*)l, 16, 0, 0);
}

__device__ __forceinline__ void stage_tile(
    const signed char* __restrict__ q, const signed char* __restrict__ w,
    char* bufA, char* bufB, int rowA0, int rowB0, int k0, int K, int tid) {
#pragma unroll
  for (int i = 0; i < 2; ++i) {
    int c  = (i << 9) + tid;                 // 0..1023: A chunks (256 rows x 4)
    int r  = c >> 2;
    int sl = (c & 3) ^ ((r >> 1) & 3);
    gload_lds16(q + (size_t)(rowA0 + r) * K + k0 + (sl << 4), bufA + (c << 4));
  }
#pragma unroll
  for (int i = 0; i < 2; ++i) {
    int c  = (i << 9) + tid;                 // 0..1023: B chunks
    int r  = c >> 2;
    int sl = (c & 3) ^ ((r >> 1) & 3);
    gload_lds16(w + (size_t)(rowB0 + r) * K + k0 + (sl << 4), bufB + (c << 4));
  }
}

__global__ __launch_bounds__(512, 2) void gemm_dequant_kernel(
    const signed char* __restrict__ q, const signed char* __restrict__ w,
    const float* __restrict__ scales, const int* __restrict__ zps,
    const int* __restrict__ sums, const float* __restrict__ bias,
    const float* __restrict__ w_scales, const int* __restrict__ w_zeros,
    const int* __restrict__ w_sums, float* __restrict__ out,
    int N, int K, int nblk) {
  __shared__ char sh[3][32768];              // per buffer: A 16K | B 16K
  const int tid  = threadIdx.x;
  const int lane = tid & 63;
  const int wave = tid >> 6;
  const int wr = wave >> 2;                  // 0..1  (M half)
  const int wc = wave & 3;                   // 0..3  (N quarter)
  const int fr = lane & 15;
  const int kb = lane >> 4;                  // 16B K-slot 0..3
  const int ntN = N >> 8;                    // 4
  // XCD-chunked swizzle (bijective: nblk % 8 == 0): xcd = bid&7 gets a
  // contiguous chunk of linear tile ids -> tileM locality within one L2.
  const int per = nblk >> 3;
  const int lin = ((int)blockIdx.x & 7) * per + ((int)blockIdx.x >> 3);
  const int rowA0 = (lin / ntN) << 8;
  const int rowB0 = (lin % ntN) << 8;
  const int wrbase = wr << 7;                // wave row base in tile
  const int wcbase = wc << 6;                // wave col base in tile

  v4i acc[8][4];
#pragma unroll
  for (int i = 0; i < 8; ++i)
#pragma unroll
    for (int j = 0; j < 4; ++j) {
      v4i z = {0, 0, 0, 0};
      acc[i][j] = z;
    }

  const int NT = K >> 6;                     // 16 K-tiles
  stage_tile(q, w, sh[0], sh[0] + 16384, rowA0, rowB0, 0, K, tid);
  stage_tile(q, w, sh[1], sh[1] + 16384, rowA0, rowB0, 64, K, tid);

  for (int t = 0; t < NT; ++t) {
    if (t + 2 < NT) {
      int b = (t + 2) % 3;
      stage_tile(q, w, sh[b], sh[b] + 16384, rowA0, rowB0, (t + 2) << 6, K, tid);
    }
    // counted wait: oldest 4 loads (this tile's) done; future tiles stay in flight
    if (t < NT - 2)      { WAITVM(8); }
    else if (t == NT - 2){ WAITVM(4); }
    else                 { WAITVM(0); }
    __builtin_amdgcn_s_barrier();

    const char* bA = sh[t % 3];
    const char* bB = bA + 16384;

    v4i bfrag[4], afrag[4];
#pragma unroll
    for (int n = 0; n < 4; ++n) {
      int rb = wcbase + (n << 4) + fr;
      bfrag[n] = *(const v4i*)(bB + (rb << 6) + ((kb ^ ((rb >> 1) & 3)) << 4));
    }
#pragma unroll
    for (int m = 0; m < 4; ++m) {
      int ra = wrbase + (m << 4) + fr;
      afrag[m] = *(const v4i*)(bA + (ra << 6) + ((kb ^ ((ra >> 1) & 3)) << 4));
    }
    __builtin_amdgcn_s_barrier();
    __builtin_amdgcn_s_setprio(1);
#pragma unroll
    for (int m = 0; m < 4; ++m)
#pragma unroll
      for (int n = 0; n < 4; ++n)
        acc[m][n] = __builtin_amdgcn_mfma_i32_16x16x64_i8(afrag[m], bfrag[n],
                                                          acc[m][n], 0, 0, 0);
    __builtin_amdgcn_s_setprio(0);
#pragma unroll
    for (int m = 0; m < 4; ++m) {
      int ra = wrbase + ((m + 4) << 4) + fr;
      afrag[m] = *(const v4i*)(bA + (ra << 6) + ((kb ^ ((ra >> 1) & 3)) << 4));
    }
    __builtin_amdgcn_s_barrier();
    __builtin_amdgcn_s_setprio(1);
#pragma unroll
    for (int m = 0; m < 4; ++m)
#pragma unroll
      for (int n = 0; n < 4; ++n)
        acc[m + 4][n] = __builtin_amdgcn_mfma_i32_16x16x64_i8(
            afrag[m], bfrag[n], acc[m + 4][n], 0, 0, 0);
    __builtin_amdgcn_s_setprio(0);
    asm volatile("" ::: "memory");
    __builtin_amdgcn_s_barrier();            // end-of-tile: buf[t%3] free
  }

  // Epilogue: C/D layout col = lane&15, row = (lane>>4)*4 + reg.
  const int baseM = rowA0 + wrbase;
  const int baseN = rowB0 + wcbase;
  const int qr = (lane >> 4) << 2;
  const int qc = lane & 15;
  float cb[4], cwsc[4];
  int cwz[4], cws[4];
#pragma unroll
  for (int n = 0; n < 4; ++n) {
    int col = baseN + (n << 4) + qc;
    cb[n]   = bias[col];
    cwsc[n] = w_scales[col];
    cwz[n]  = w_zeros[col];
    cws[n]  = w_sums[col];
  }
#pragma unroll
  for (int i = 0; i < 8; ++i) {
    const int m0 = baseM + (i << 4) + qr;
    float sc[4];
    int zp4[4], sm4[4];
#pragma unroll
    for (int j = 0; j < 4; ++j) {
      sc[j]  = scales[m0 + j];
      zp4[j] = zps[m0 + j];
      sm4[j] = sums[m0 + j];
    }
#pragma unroll
    for (int n = 0; n < 4; ++n) {
      const int col = baseN + (n << 4) + qc;
#pragma unroll
      for (int j = 0; j < 4; ++j) {
        int d    = acc[i][n][j];
        int temp = zp4[j] * cws[n] + sm4[j] * cwz[n];
        out[(size_t)(m0 + j) * N + col] = cb[n] + (float)(d - temp) * (sc[j] * cwsc[n]);
      }
    }
  }
}

extern "C" void kernel_launch(void* const* d_in, const int* in_sizes, int n_in,
                              void* d_out, int out_size, void* d_ws, size_t ws_size,
                              hipStream_t stream) {
  const float* inp      = (const float*)d_in[0];
  const int*   qw32     = (const int*)d_in[1];   // int8 in ref -> int32 on device
  const float* bias     = (const float*)d_in[2];
  const float* w_scales = (const float*)d_in[3];
  const int*   w_zeros  = (const int*)d_in[4];
  const int*   w_sums   = (const int*)d_in[5];

  const int N = in_sizes[2];      // 1024
  const int K = in_sizes[1] / N;  // 1024
  const int M = in_sizes[0] / K;  // 16384

  float*       scales = (float*)d_ws;
  int*         zps    = (int*)((char*)d_ws + (size_t)M * 4);
  int*         sums   = (int*)((char*)d_ws + (size_t)M * 8);
  signed char* q      = (signed char*)((char*)d_ws + (size_t)M * 12);
  signed char* w8     = (signed char*)((char*)d_ws + (size_t)M * 12 + (size_t)M * K);

  const int n4 = (N * K) / 4;
  const int nblk = (M / 256) * (N / 256);
  pack_w_kernel<<<(n4 + 255) / 256, 256, 0, stream>>>(qw32, (int*)w8, n4);
  quant_rows_kernel<<<M / 4, 256, 0, stream>>>(inp, q, scales, zps, sums, K);
  gemm_dequant_kernel<<<nblk, 512, 0, stream>>>(
      q, w8, scales, zps, sums, bias, w_scales, w_zeros, w_sums,
      (float*)d_out, N, K, nblk);
}